// Round 7
// baseline (717.425 us; speedup 1.0000x reference)
//
#include <hip/hip_runtime.h>
#include <hip/hip_bf16.h>
#include <cstdint>

#define DEV_INLINE __device__ __forceinline__

// problem constants
constexpr int N0n = 100000, N1n = 25000, N2n = 6250;
constexpr int E0n = 800000, E1n = 200000, E2n = 50000;
constexpr int NT  = N0n + N1n + N2n;     // 131250 concatenated node space
constexpr int ET  = E0n + E1n + E2n;     // 1050000 concatenated edge space
constexpr int Bn  = 2;

DEV_INLINE float lrelu(float x) { return x > 0.f ? x : 0.01f * x; }

// ---------------- CSR build (full + unpool-filtered), 3 graphs concatenated ----------

// full degree + filtered degree (src < nnz of the level's unpool) in one pass
__global__ __launch_bounds__(256) void k_deg_count(const int* __restrict__ g0,
                                                   const int* __restrict__ g1,
                                                   const int* __restrict__ g2,
                                                   int* __restrict__ deg,
                                                   int* __restrict__ deg_f) {
    int e = blockIdx.x * 256 + threadIdx.x;
    int gd; bool val;
    if (e < E0n)            { gd = g0[E0n + e];                       val = g0[e] < N1n; }
    else if (e < E0n + E1n) { int le = e - E0n;  gd = N0n + g1[E1n + le];        val = g1[le] < N2n; }
    else if (e < ET)        { int le = e - E0n - E1n; gd = N0n + N1n + g2[E2n + le]; val = true; }
    else return;
    atomicAdd(&deg[gd], 1);
    if (val) atomicAdd(&deg_f[gd], 1);
}

constexpr int SCAN_CHUNK = 2048;
constexpr int NCHUNK = (NT + SCAN_CHUNK - 1) / SCAN_CHUNK;   // 65

__global__ __launch_bounds__(256) void k_scan1(const int* __restrict__ deg,
                                               int* __restrict__ out,
                                               int* __restrict__ partials) {
    __shared__ int sums[256];
    const int chunk = blockIdx.x, t = threadIdx.x;
    const int base = chunk * SCAN_CHUNK + t * 8;
    int v[8]; int s = 0;
#pragma unroll
    for (int i = 0; i < 8; i++) { int idx = base + i; v[i] = (idx < NT) ? deg[idx] : 0; s += v[i]; }
    int val = s;
    sums[t] = val; __syncthreads();
    for (int off = 1; off < 256; off <<= 1) {
        int y = (t >= off) ? sums[t - off] : 0;
        __syncthreads();
        val += y; sums[t] = val;
        __syncthreads();
    }
    const int excl = val - s;
    if (t == 255) partials[chunk] = val;
    int run = excl;
#pragma unroll
    for (int i = 0; i < 8; i++) { int idx = base + i; if (idx < NT) out[idx] = run; run += v[i]; }
}

// scan partials in-block (LDS) + add to offsets; also writes offsets[NT] = total.
__global__ __launch_bounds__(256) void k_scan23(const int* __restrict__ partials,
                                                int* __restrict__ offsets) {
    __shared__ int sp[128];
    const int t = threadIdx.x;
    if (t < 128) sp[t] = (t < NCHUNK) ? partials[t] : 0;
    __syncthreads();
    for (int off = 1; off < 128; off <<= 1) {
        int v = 0;
        if (t < 128) { v = sp[t]; if (t >= off) v += sp[t - off]; }
        __syncthreads();
        if (t < 128) sp[t] = v;
        __syncthreads();
    }
    const int idx = blockIdx.x * 256 + t;
    if (idx < NT) {
        const int c = idx / SCAN_CHUNK;
        if (c > 0) offsets[idx] += sp[c - 1];
    }
    if (blockIdx.x == 0 && t == 0) offsets[NT] = sp[NCHUNK - 1];
}

__global__ __launch_bounds__(256) void k_csr_fill(const int* __restrict__ g0,
                                                  const int* __restrict__ g1,
                                                  const int* __restrict__ g2,
                                                  const int* __restrict__ offsets,
                                                  const int* __restrict__ foffsets,
                                                  int* __restrict__ cursor,
                                                  int* __restrict__ cursor_f,
                                                  int* __restrict__ csr,
                                                  int* __restrict__ csr_f) {
    int e = blockIdx.x * 256 + threadIdx.x;
    int src, gd; bool val;
    if (e < E0n)            { src = g0[e];            gd = g0[E0n + e];              val = src < N1n; }
    else if (e < E0n + E1n) { int le = e - E0n;       src = g1[le]; gd = N0n + g1[E1n + le];  val = src < N2n; }
    else if (e < ET)        { int le = e - E0n - E1n; src = g2[le]; gd = N0n + N1n + g2[E2n + le]; val = true; }
    else return;
    int pos = offsets[gd] + atomicAdd(&cursor[gd], 1);
    csr[pos] = src;
    if (val) {
        int pf = foffsets[gd] + atomicAdd(&cursor_f[gd], 1);
        csr_f[pf] = src;
    }
}

// ---------------- latent MLP: z -> x0 [N2, B, 128] ----------------

__global__ __launch_bounds__(256) void k_latent(const float* __restrict__ z,
                                                const float* __restrict__ W1,
                                                const float* __restrict__ b1,
                                                const float* __restrict__ W2,
                                                const float* __restrict__ b2,
                                                float* __restrict__ x0) {
    __shared__ float col[64];
    const int t = threadIdx.x;
    const int b = t >> 7, l = t & 127;
    const float zv = z[b * 128 + l];
    float h1[64];
#pragma unroll
    for (int k = 0; k < 64; k++) h1[k] = lrelu(zv * W1[k] + b1[k]);
    for (int nn = 0; nn < 8; nn++) {
        const int n = blockIdx.x * 8 + nn;
        if (n >= N2n) break;                 // uniform across block
        if (t < 64) col[t] = W2[t * N2n + n];
        __syncthreads();
        float s = b2[n];
#pragma unroll
        for (int k = 0; k < 64; k++) s += h1[k] * col[k];
        x0[((size_t)n * Bn + b) * 128 + l] = s;
        __syncthreads();
    }
}

// ---------------- dual GEMM: U = x(Wa-Wb)+b, V = x*Wb ----------------
// 128x64 tile, 8x4 per thread. x: [Mrows,K] fp32; W: [2K,COUT] fp32; compact out.

template <int K, int COUT>
__global__ __launch_bounds__(256) void k_gemm_uv(const float* __restrict__ x,
                                                 const float* __restrict__ W,
                                                 const float* __restrict__ bias,
                                                 float* __restrict__ U, float* __restrict__ V,
                                                 int Mrows) {
    constexpr int TM = 128, TN = 64, TK = 32;
    __shared__ float xs[TK][TM + 4];
    __shared__ float wd[TK][TN];
    __shared__ float wb[TK][TN];
    const int t = threadIdx.x;
    const int row0 = blockIdx.x * TM;
    const int col0 = blockIdx.y * TN;
    const int tc = (t & 15) * 4;        // 16 col groups * 4
    const int tr = (t >> 4) * 8;        // 16 row groups * 8
    const int lrow = t >> 1;            // x-load: 128 rows, 2 thr/row
    const int lseg = (t & 1) * 16;      // x-load: 16 consecutive k
    const int wrow = t >> 3;            // w-load: 32 k rows
    const int wseg = (t & 7) * 8;       // w-load: 8 cols
    float accU[8][4] = {}, accV[8][4] = {};

    for (int k0 = 0; k0 < K; k0 += TK) {
        __syncthreads();
        {   // x tile: 4 float4 per thread, transposed store
            float4 a[4] = {{0,0,0,0},{0,0,0,0},{0,0,0,0},{0,0,0,0}};
            const int gr = row0 + lrow;
            if (gr < Mrows) {
                const float4* p = (const float4*)(x + (size_t)gr * K + k0 + lseg);
                a[0] = p[0]; a[1] = p[1]; a[2] = p[2]; a[3] = p[3];
            }
#pragma unroll
            for (int q = 0; q < 4; q++) {
                xs[lseg + 4 * q + 0][lrow] = a[q].x;
                xs[lseg + 4 * q + 1][lrow] = a[q].y;
                xs[lseg + 4 * q + 2][lrow] = a[q].z;
                xs[lseg + 4 * q + 3][lrow] = a[q].w;
            }
        }
        {   // W tiles: rows [0,K) = Wa (mult x_i), rows [K,2K) = Wb (mult x_j - x_i)
            const float* wa = W + (size_t)(k0 + wrow) * COUT + col0 + wseg;
            const float* wbp = wa + (size_t)K * COUT;
            float fa[8], fb[8];
            *(float4*)&fa[0] = ((const float4*)wa)[0];
            *(float4*)&fa[4] = ((const float4*)wa)[1];
            *(float4*)&fb[0] = ((const float4*)wbp)[0];
            *(float4*)&fb[4] = ((const float4*)wbp)[1];
#pragma unroll
            for (int i = 0; i < 8; i++) {
                wd[wrow][wseg + i] = fa[i] - fb[i];
                wb[wrow][wseg + i] = fb[i];
            }
        }
        __syncthreads();
#pragma unroll
        for (int kk = 0; kk < TK; ++kk) {
            const float4 a0 = *(const float4*)&xs[kk][tr];
            const float4 a1 = *(const float4*)&xs[kk][tr + 4];
            const float4 d = *(const float4*)&wd[kk][tc];
            const float4 e = *(const float4*)&wb[kk][tc];
            const float av[8] = {a0.x, a0.y, a0.z, a0.w, a1.x, a1.y, a1.z, a1.w};
            const float dv[4] = {d.x, d.y, d.z, d.w};
            const float ev[4] = {e.x, e.y, e.z, e.w};
#pragma unroll
            for (int i = 0; i < 8; i++)
#pragma unroll
                for (int j = 0; j < 4; j++) {
                    accU[i][j] += av[i] * dv[j];
                    accV[i][j] += av[i] * ev[j];
                }
        }
    }
    float bf4[4];
#pragma unroll
    for (int j = 0; j < 4; j++) bf4[j] = bias[col0 + tc + j];
#pragma unroll
    for (int i = 0; i < 8; i++) {
        const int r = row0 + tr + i;
        if (r < Mrows) {
            const size_t orow = (size_t)r * COUT + col0 + tc;
            float4 uo = {accU[i][0] + bf4[0], accU[i][1] + bf4[1],
                         accU[i][2] + bf4[2], accU[i][3] + bf4[3]};
            float4 vo = {accV[i][0], accV[i][1], accV[i][2], accV[i][3]};
            *(float4*)(U + orow) = uo;
            *(float4*)(V + orow) = vo;
        }
    }
}

// ---------------- dense edge agg (float4/lane, 8-deep gather pipeline) ----------

DEV_INLINE void acc_relu4(float4& acc, const float4 u, const float4 v) {
    acc.x += fmaxf(u.x + v.x, 0.f);
    acc.y += fmaxf(u.y + v.y, 0.f);
    acc.z += fmaxf(u.z + v.z, 0.f);
    acc.w += fmaxf(u.w + v.w, 0.f);
}

template <int C>
__global__ __launch_bounds__(256) void k_edge_agg(const float* __restrict__ U,
                                                  const float* __restrict__ V,
                                                  const int* __restrict__ offsets,
                                                  const int* __restrict__ csr,
                                                  int nbase, int nnodes,
                                                  float* __restrict__ out) {
    constexpr int TPN = C / 4;
    constexpr int NPB = 256 / TPN;
    const int t = threadIdx.x;
    const int sub = t / TPN;
    const int c4 = (t % TPN) * 4;
    const int i = blockIdx.x * NPB + sub;
    if (i >= nnodes) return;
    const int gi = nbase + i;
    const int beg = offsets[gi], end = offsets[gi + 1];
    const float4 u = *(const float4*)&U[(size_t)i * C + c4];
    float4 acc = {0, 0, 0, 0};
    int e = beg;
    for (; e + 8 <= end; e += 8) {
        int j[8];
#pragma unroll
        for (int q = 0; q < 8; q++) j[q] = csr[e + q];
        float4 v[8];
#pragma unroll
        for (int q = 0; q < 8; q++) v[q] = *(const float4*)&V[(size_t)j[q] * C + c4];
#pragma unroll
        for (int q = 0; q < 8; q++) acc_relu4(acc, u, v[q]);
    }
    if (e + 4 <= end) {
        const int j0 = csr[e], j1 = csr[e + 1], j2 = csr[e + 2], j3 = csr[e + 3];
        const float4 v0 = *(const float4*)&V[(size_t)j0 * C + c4];
        const float4 v1 = *(const float4*)&V[(size_t)j1 * C + c4];
        const float4 v2 = *(const float4*)&V[(size_t)j2 * C + c4];
        const float4 v3 = *(const float4*)&V[(size_t)j3 * C + c4];
        acc_relu4(acc, u, v0); acc_relu4(acc, u, v1);
        acc_relu4(acc, u, v2); acc_relu4(acc, u, v3);
        e += 4;
    }
    for (; e < end; ++e) {
        const float4 v = *(const float4*)&V[(size_t)csr[e] * C + c4];
        acc_relu4(acc, u, v);
    }
    const int dg = end - beg;
    const float inv = 1.f / (float)(dg > 0 ? dg : 1);
    float4 o = {acc.x * inv, acc.y * inv, acc.z * inv, acc.w * inv};
    *(float4*)&out[(size_t)i * C + c4] = o;
}

// ---------------- fused dual agg over FILTERED csr ----------------
// out[i] = lrelu( [ (deg-deg_f)*(relu(u2)+relu(usk)) + sum_{valid j} relu(u2+v2_j)+relu(usk+vsk_j) ] / deg )
// compact U/V on [0,nnz); i>=nnz -> u = bias row.

template <int C>
__global__ __launch_bounds__(256) void k_edge_agg_fused(const float* __restrict__ U2,
                                                        const float* __restrict__ V2,
                                                        const float* __restrict__ Usk,
                                                        const float* __restrict__ Vsk,
                                                        const float* __restrict__ b2,
                                                        const float* __restrict__ bsk,
                                                        const int* __restrict__ offsets,
                                                        const int* __restrict__ foffsets,
                                                        const int* __restrict__ csr_f,
                                                        int nbase, int nnodes, int nnz,
                                                        float* __restrict__ out) {
    constexpr int COUTc = C / Bn;
    constexpr int TPN = C / 4;
    constexpr int NPB = 256 / TPN;
    const int t = threadIdx.x;
    const int sub = t / TPN;
    const int c4 = (t % TPN) * 4;
    const int i = blockIdx.x * NPB + sub;
    if (i >= nnodes) return;
    const int gi = nbase + i;
    const int dg = offsets[gi + 1] - offsets[gi];
    const int fb = foffsets[gi], fe = foffsets[gi + 1];
    const int cb = c4 & (COUTc - 1);
    const float4 u2  = (i < nnz) ? *(const float4*)&U2[(size_t)i * C + c4]
                                 : *(const float4*)&b2[cb];
    const float4 usk = (i < nnz) ? *(const float4*)&Usk[(size_t)i * C + c4]
                                 : *(const float4*)&bsk[cb];
    const float cn = (float)(dg - (fe - fb));   // edges with zero-src: constant message
    float4 acc;
    acc.x = cn * (fmaxf(u2.x, 0.f) + fmaxf(usk.x, 0.f));
    acc.y = cn * (fmaxf(u2.y, 0.f) + fmaxf(usk.y, 0.f));
    acc.z = cn * (fmaxf(u2.z, 0.f) + fmaxf(usk.z, 0.f));
    acc.w = cn * (fmaxf(u2.w, 0.f) + fmaxf(usk.w, 0.f));
    int e = fb;
    for (; e + 4 <= fe; e += 4) {
        const int j0 = csr_f[e], j1 = csr_f[e + 1], j2 = csr_f[e + 2], j3 = csr_f[e + 3];
        const float4 p0 = *(const float4*)&V2[(size_t)j0 * C + c4];
        const float4 p1 = *(const float4*)&V2[(size_t)j1 * C + c4];
        const float4 p2 = *(const float4*)&V2[(size_t)j2 * C + c4];
        const float4 p3 = *(const float4*)&V2[(size_t)j3 * C + c4];
        const float4 q0 = *(const float4*)&Vsk[(size_t)j0 * C + c4];
        const float4 q1 = *(const float4*)&Vsk[(size_t)j1 * C + c4];
        const float4 q2 = *(const float4*)&Vsk[(size_t)j2 * C + c4];
        const float4 q3 = *(const float4*)&Vsk[(size_t)j3 * C + c4];
        acc_relu4(acc, u2, p0); acc_relu4(acc, u2, p1); acc_relu4(acc, u2, p2); acc_relu4(acc, u2, p3);
        acc_relu4(acc, usk, q0); acc_relu4(acc, usk, q1); acc_relu4(acc, usk, q2); acc_relu4(acc, usk, q3);
    }
    for (; e < fe; ++e) {
        const int j = csr_f[e];
        const float4 pv = *(const float4*)&V2[(size_t)j * C + c4];
        const float4 qv = *(const float4*)&Vsk[(size_t)j * C + c4];
        acc_relu4(acc, u2, pv); acc_relu4(acc, usk, qv);
    }
    const float inv = 1.f / (float)(dg > 0 ? dg : 1);
    float4 o = {lrelu(acc.x * inv), lrelu(acc.y * inv),
                lrelu(acc.z * inv), lrelu(acc.w * inv)};
    *(float4*)&out[(size_t)i * C + c4] = o;
}

// ---------------- fused final agg + decoder MLP + LayerNorm(3) ----------------

__global__ __launch_bounds__(256) void k_agg_dec(const float* __restrict__ U,
                                                 const float* __restrict__ V,
                                                 const int* __restrict__ offsets,
                                                 const int* __restrict__ csr,
                                                 const float* __restrict__ Wd1,
                                                 const float* __restrict__ bd1,
                                                 const float* __restrict__ Wd2,
                                                 const float* __restrict__ bd2,
                                                 const float* __restrict__ gamma,
                                                 const float* __restrict__ beta,
                                                 float* __restrict__ out) {
    constexpr int C = 128;
    __shared__ float w1[2048];          // Wd1 [64,32]
    __shared__ float w2[96];            // Wd2 [32,3]
    __shared__ float sb1[32], sb2[3], sg[3], sbt[3];
    __shared__ float xs[16 * 66];       // 16 (n,b) rows of 64, stride 66
    __shared__ float hs[16][33];        // h1 per row
    const int t = threadIdx.x;
    for (int i = t; i < 2048; i += 256) w1[i] = Wd1[i];
    if (t < 96) w2[t] = Wd2[t];
    if (t < 32) sb1[t] = bd1[t];
    if (t < 3) { sb2[t] = bd2[t]; sg[t] = gamma[t]; sbt[t] = beta[t]; }

    // --- agg phase: 8 nodes/block, 32 thr/node, float4/lane, 8-deep pipeline ---
    const int sub = t >> 5;
    const int c4 = (t & 31) * 4;        // channel = b*64 + k
    const int i0 = blockIdx.x * 8 + sub;
    float4 r = {0, 0, 0, 0};
    if (i0 < N0n) {
        const int beg = offsets[i0], end = offsets[i0 + 1];
        const float4 u = *(const float4*)&U[(size_t)i0 * C + c4];
        float4 acc = {0, 0, 0, 0};
        int e = beg;
        for (; e + 8 <= end; e += 8) {
            int j[8];
#pragma unroll
            for (int q = 0; q < 8; q++) j[q] = csr[e + q];
            float4 v[8];
#pragma unroll
            for (int q = 0; q < 8; q++) v[q] = *(const float4*)&V[(size_t)j[q] * C + c4];
#pragma unroll
            for (int q = 0; q < 8; q++) acc_relu4(acc, u, v[q]);
        }
        if (e + 4 <= end) {
            const int j0 = csr[e], j1 = csr[e + 1], j2 = csr[e + 2], j3 = csr[e + 3];
            const float4 v0 = *(const float4*)&V[(size_t)j0 * C + c4];
            const float4 v1 = *(const float4*)&V[(size_t)j1 * C + c4];
            const float4 v2 = *(const float4*)&V[(size_t)j2 * C + c4];
            const float4 v3 = *(const float4*)&V[(size_t)j3 * C + c4];
            acc_relu4(acc, u, v0); acc_relu4(acc, u, v1);
            acc_relu4(acc, u, v2); acc_relu4(acc, u, v3);
            e += 4;
        }
        for (; e < end; ++e) {
            const float4 v = *(const float4*)&V[(size_t)csr[e] * C + c4];
            acc_relu4(acc, u, v);
        }
        const int dg = end - beg;
        const float inv = 1.f / (float)(dg > 0 ? dg : 1);
        r = {acc.x * inv, acc.y * inv, acc.z * inv, acc.w * inv};
    }
    // stage into LDS: row = sub*2 + b, col = k
    {
        const int rrow = sub * 2 + (c4 >> 6);
        const int rk = c4 & 63;
        float* xp = &xs[rrow * 66 + rk];
        xp[0] = r.x; xp[1] = r.y; xp[2] = r.z; xp[3] = r.w;
    }
    __syncthreads();

    // --- decoder phase: 16 rows x 16 threads ---
    const int drow = t >> 4;
    const int l16 = t & 15;
    float h1a = sb1[l16], h1b = sb1[l16 + 16];
    const float* xrow = &xs[drow * 66];
#pragma unroll 8
    for (int k = 0; k < 64; k++) {
        const float xk = xrow[k];
        h1a += xk * w1[k * 32 + l16];
        h1b += xk * w1[k * 32 + l16 + 16];
    }
    hs[drow][l16] = lrelu(h1a);
    hs[drow][l16 + 16] = lrelu(h1b);
    __syncthreads();

    // --- h2 + LN: one thread per row ---
    if (t < 16) {
        const int node = t >> 1, b = t & 1;
        const int n = blockIdx.x * 8 + node;
        if (n < N0n) {
            float h2[3];
#pragma unroll
            for (int j = 0; j < 3; j++) {
                float s = sb2[j];
#pragma unroll
                for (int c = 0; c < 32; c++) s += hs[t][c] * w2[c * 3 + j];
                h2[j] = s;
            }
            const float mu = (h2[0] + h2[1] + h2[2]) * (1.f / 3.f);
            const float d0 = h2[0] - mu, d1 = h2[1] - mu, d2 = h2[2] - mu;
            const float var = (d0 * d0 + d1 * d1 + d2 * d2) * (1.f / 3.f);
            const float inv = rsqrtf(var + 1e-5f);
            const size_t ob = (size_t)b * N0n * 3 + (size_t)n * 3;
            out[ob + 0] = d0 * inv * sg[0] + sbt[0];
            out[ob + 1] = d1 * inv * sg[1] + sbt[1];
            out[ob + 2] = d2 * inv * sg[2] + sbt[2];
        }
    }
}

// ---------------- launch ----------------

extern "C" void kernel_launch(void* const* d_in, const int* in_sizes, int n_in,
                              void* d_out, int out_size, void* d_ws, size_t ws_size,
                              hipStream_t stream) {
    (void)in_sizes; (void)n_in; (void)out_size; (void)ws_size;
    const float* z   = (const float*)d_in[0];
    const int* g0    = (const int*)d_in[1];
    const int* g1    = (const int*)d_in[2];
    const int* g2    = (const int*)d_in[3];
    const float* W_up1 = (const float*)d_in[6];
    const float* b_up1 = (const float*)d_in[7];
    const float* W_up2 = (const float*)d_in[8];
    const float* b_up2 = (const float*)d_in[9];
    const float* Wb    = (const float*)d_in[10];
    const float* bb    = (const float*)d_in[11];
    const float* l0_W1 = (const float*)d_in[12];
    const float* l0_b1 = (const float*)d_in[13];
    const float* l0_W2 = (const float*)d_in[14];
    const float* l0_b2 = (const float*)d_in[15];
    const float* l0_Wsk = (const float*)d_in[16];
    const float* l0_bsk = (const float*)d_in[17];
    const float* l1_W1 = (const float*)d_in[18];
    const float* l1_b1 = (const float*)d_in[19];
    const float* l1_W2 = (const float*)d_in[20];
    const float* l1_b2 = (const float*)d_in[21];
    const float* l1_Wsk = (const float*)d_in[22];
    const float* l1_bsk = (const float*)d_in[23];
    const float* Wf    = (const float*)d_in[24];
    const float* bf_   = (const float*)d_in[25];
    const float* Wd1   = (const float*)d_in[26];
    const float* bd1   = (const float*)d_in[27];
    const float* Wd2   = (const float*)d_in[28];
    const float* bd2   = (const float*)d_in[29];
    const float* gamma = (const float*)d_in[30];
    const float* beta  = (const float*)d_in[31];

    char* p = (char*)d_ws;
    auto alloc = [&](size_t bytes) -> char* {
        char* r = p; p += (bytes + 255) & ~(size_t)255; return r;
    };
    int* offsets   = (int*)alloc((size_t)(NT + 1) * 4);
    int* foffsets  = (int*)alloc((size_t)(NT + 1) * 4);
    int* partials  = (int*)alloc(128 * 4);
    int* partials_f= (int*)alloc(128 * 4);
    int* degcur    = (int*)alloc((size_t)4 * NT * 4);
    int* deg = degcur; int* cursor = degcur + NT;
    int* deg_f = degcur + 2 * NT; int* cursor_f = degcur + 3 * NT;
    int* csr   = (int*)alloc((size_t)ET * 4);
    int* csr_f = (int*)alloc((size_t)ET * 4);

    // pooled slabs (fp32): A,B,C = 12.8M floats (51.2 MB) each, D = 3.2M floats.
    constexpr size_t SLOT = (size_t)N0n * Bn * 64;   // 12.8M floats
    constexpr size_t M1 = 1600000;                    // 1.6M-float granule
    float* A = (float*)alloc(SLOT * 4);
    float* B = (float*)alloc(SLOT * 4);
    float* C = (float*)alloc(SLOT * 4);
    float* D = (float*)alloc((size_t)N1n * Bn * 64 * 4);

    // --- CSR build (full + filtered) ---
    hipMemsetAsync(degcur, 0, (size_t)4 * NT * 4, stream);
    k_deg_count<<<(ET + 255) / 256, 256, 0, stream>>>(g0, g1, g2, deg, deg_f);
    k_scan1<<<NCHUNK, 256, 0, stream>>>(deg, offsets, partials);
    k_scan1<<<NCHUNK, 256, 0, stream>>>(deg_f, foffsets, partials_f);
    k_scan23<<<(NT + 255) / 256, 256, 0, stream>>>(partials, offsets);
    k_scan23<<<(NT + 255) / 256, 256, 0, stream>>>(partials_f, foffsets);
    k_csr_fill<<<(ET + 255) / 256, 256, 0, stream>>>(g0, g1, g2, offsets, foffsets,
                                                     cursor, cursor_f, csr, csr_f);

    const int nb2 = N0n + N1n;   // g2 node base in offsets
    const int nb1 = N0n;         // g1 node base

    // --- latent -> x0 [N2,B,128] @ A[0,M1) ---
    float* x0 = A;
    k_latent<<<(N2n + 7) / 8, 256, 0, stream>>>(z, W_up1, b_up1, W_up2, b_up2, x0);

    // --- conv1 (g2, 128->256): U@A[M1,3M1) V@A[3M1,5M1) -> xc1 @ A[5M1,7M1) ---
    float* xc1 = A + 5 * M1;
    k_gemm_uv<128, 256><<<dim3(98, 4), 256, 0, stream>>>(x0, Wb, bb, A + M1, A + 3 * M1, N2n * Bn);
    k_edge_agg<512><<<(N2n + 1) / 2, 256, 0, stream>>>(A + M1, A + 3 * M1, offsets, csr, nb2, N2n, xc1);

    // --- l0_W1 (g2, 256->64): U@A[7M1,+.5) V@A[7.5M1,8M1) -> t1 @ A[0,M1) (x0 dead) ---
    float* t1 = A;
    k_gemm_uv<256, 64><<<dim3(98, 1), 256, 0, stream>>>(xc1, l0_W1, l0_b1,
                                                        A + 7 * M1, A + 7 * M1 + 800000, N2n * Bn);
    k_edge_agg<128><<<(N2n + 7) / 8, 256, 0, stream>>>(A + 7 * M1, A + 7 * M1 + 800000,
                                                       offsets, csr, nb2, N2n, t1);

    // --- l0_W2 GEMM (64->128): t1 -> U2@B[0,M1) V2@B[M1,2M1) ---
    k_gemm_uv<64, 128><<<dim3(98, 2), 256, 0, stream>>>(t1, l0_W2, l0_b2, B, B + M1, N2n * Bn);
    // --- skip0 GEMM (256->128): xc1 -> Usk@B[2M1,3M1) Vsk@B[3M1,4M1) ---
    k_gemm_uv<256, 128><<<dim3(98, 2), 256, 0, stream>>>(xc1, l0_Wsk, l0_bsk,
                                                         B + 2 * M1, B + 3 * M1, N2n * Bn);
    // --- fused layer0 agg (g1, C=256, nnz=N2n, FILTERED): -> x1 @ B[4M1,8M1) ---
    float* x1 = B + 4 * M1;
    k_edge_agg_fused<256><<<(N1n + 3) / 4, 256, 0, stream>>>(B, B + M1, B + 2 * M1, B + 3 * M1,
                                                             l0_b2, l0_bsk, offsets, foffsets, csr_f,
                                                             nb1, N1n, N2n, x1);

    // --- l1_W1 (g1, 128->64): U@A[0,2M1) V@A[2M1,4M1) -> t2 @ D ---
    float* t2 = D;
    k_gemm_uv<128, 64><<<dim3(391, 1), 256, 0, stream>>>(x1, l1_W1, l1_b1, A, A + 2 * M1, N1n * Bn);
    k_edge_agg<128><<<(N1n + 7) / 8, 256, 0, stream>>>(A, A + 2 * M1, offsets, csr, nb1, N1n, t2);

    // --- l1_W2 GEMM (64->64): t2 -> U2@A[0,2M1) V2@A[2M1,4M1) ---
    k_gemm_uv<64, 64><<<dim3(391, 1), 256, 0, stream>>>(t2, l1_W2, l1_b2, A, A + 2 * M1, N1n * Bn);
    // --- skip1 GEMM (128->64): x1 -> Usk@A[4M1,6M1) Vsk@A[6M1,8M1) ---
    k_gemm_uv<128, 64><<<dim3(391, 1), 256, 0, stream>>>(x1, l1_Wsk, l1_bsk,
                                                         A + 4 * M1, A + 6 * M1, N1n * Bn);
    // --- fused layer1 agg (g0, C=128, nnz=N1n, FILTERED): -> x2 @ C ---
    float* x2 = C;
    k_edge_agg_fused<128><<<(N0n + 7) / 8, 256, 0, stream>>>(A, A + 2 * M1, A + 4 * M1, A + 6 * M1,
                                                             l1_b2, l1_bsk, offsets, foffsets, csr_f,
                                                             0, N0n, N1n, x2);

    // --- final conv (g0, 64->64): x2 -> Uf@A (full) Vf@B (full) ---
    k_gemm_uv<64, 64><<<dim3(1563, 1), 256, 0, stream>>>(x2, Wf, bf_, A, B, N0n * Bn);
    // --- fused final agg + decoder + LN -> d_out ---
    k_agg_dec<<<(N0n + 7) / 8, 256, 0, stream>>>(A, B, offsets, csr,
                                                 Wd1, bd1, Wd2, bd2, gamma, beta,
                                                 (float*)d_out);
}

// Round 8
// 670.887 us; speedup vs baseline: 1.0694x; 1.0694x over previous
//
#include <hip/hip_runtime.h>
#include <hip/hip_bf16.h>
#include <cstdint>

#define DEV_INLINE __device__ __forceinline__

// problem constants
constexpr int N0n = 100000, N1n = 25000, N2n = 6250;
constexpr int E0n = 800000, E1n = 200000, E2n = 50000;
constexpr int NT  = N0n + N1n + N2n;     // 131250 concatenated node space
constexpr int ET  = E0n + E1n + E2n;     // 1050000 concatenated edge space
constexpr int Bn  = 2;

DEV_INLINE float lrelu(float x) { return x > 0.f ? x : 0.01f * x; }

typedef float f32x4 __attribute__((ext_vector_type(4)));
DEV_INLINE float4 ntload4(const float* p) {
    f32x4 v = __builtin_nontemporal_load((const f32x4*)p);
    float4 r; r.x = v.x; r.y = v.y; r.z = v.z; r.w = v.w; return r;
}

// ---------------- CSR build: single csr, valid-prefix partitioned per node ----------
// "valid" = src id < nnz of the level's unpool (edges whose src row is non-zero
// in the unpooled tensor). g2 edges are all valid.

__global__ __launch_bounds__(256) void k_deg_count(const int* __restrict__ g0,
                                                   const int* __restrict__ g1,
                                                   const int* __restrict__ g2,
                                                   int* __restrict__ deg,
                                                   int* __restrict__ deg_f) {
    int e = blockIdx.x * 256 + threadIdx.x;
    int gd; bool val;
    if (e < E0n)            { gd = g0[E0n + e];                            val = g0[e] < N1n; }
    else if (e < E0n + E1n) { int le = e - E0n;  gd = N0n + g1[E1n + le];  val = g1[le] < N2n; }
    else if (e < ET)        { int le = e - E0n - E1n; gd = N0n + N1n + g2[E2n + le]; val = true; }
    else return;
    atomicAdd(&deg[gd], 1);
    if (val) atomicAdd(&deg_f[gd], 1);
}

constexpr int SCAN_CHUNK = 2048;
constexpr int NCHUNK = (NT + SCAN_CHUNK - 1) / SCAN_CHUNK;   // 65

__global__ __launch_bounds__(256) void k_scan1(const int* __restrict__ deg,
                                               int* __restrict__ out,
                                               int* __restrict__ partials) {
    __shared__ int sums[256];
    const int chunk = blockIdx.x, t = threadIdx.x;
    const int base = chunk * SCAN_CHUNK + t * 8;
    int v[8]; int s = 0;
#pragma unroll
    for (int i = 0; i < 8; i++) { int idx = base + i; v[i] = (idx < NT) ? deg[idx] : 0; s += v[i]; }
    int val = s;
    sums[t] = val; __syncthreads();
    for (int off = 1; off < 256; off <<= 1) {
        int y = (t >= off) ? sums[t - off] : 0;
        __syncthreads();
        val += y; sums[t] = val;
        __syncthreads();
    }
    const int excl = val - s;
    if (t == 255) partials[chunk] = val;
    int run = excl;
#pragma unroll
    for (int i = 0; i < 8; i++) { int idx = base + i; if (idx < NT) out[idx] = run; run += v[i]; }
}

// scan partials in-block (LDS) + add to offsets; also writes offsets[NT] = total.
__global__ __launch_bounds__(256) void k_scan23(const int* __restrict__ partials,
                                                int* __restrict__ offsets) {
    __shared__ int sp[128];
    const int t = threadIdx.x;
    if (t < 128) sp[t] = (t < NCHUNK) ? partials[t] : 0;
    __syncthreads();
    for (int off = 1; off < 128; off <<= 1) {
        int v = 0;
        if (t < 128) { v = sp[t]; if (t >= off) v += sp[t - off]; }
        __syncthreads();
        if (t < 128) sp[t] = v;
        __syncthreads();
    }
    const int idx = blockIdx.x * 256 + t;
    if (idx < NT) {
        const int c = idx / SCAN_CHUNK;
        if (c > 0) offsets[idx] += sp[c - 1];
    }
    if (blockIdx.x == 0 && t == 0) offsets[NT] = sp[NCHUNK - 1];
}

__global__ __launch_bounds__(256) void k_csr_fill(const int* __restrict__ g0,
                                                  const int* __restrict__ g1,
                                                  const int* __restrict__ g2,
                                                  const int* __restrict__ offsets,
                                                  const int* __restrict__ deg_f,
                                                  int* __restrict__ cur_v,
                                                  int* __restrict__ cur_i,
                                                  int* __restrict__ csr) {
    int e = blockIdx.x * 256 + threadIdx.x;
    int src, gd; bool val;
    if (e < E0n)            { src = g0[e];            gd = g0[E0n + e];              val = src < N1n; }
    else if (e < E0n + E1n) { int le = e - E0n;       src = g1[le]; gd = N0n + g1[E1n + le];  val = src < N2n; }
    else if (e < ET)        { int le = e - E0n - E1n; src = g2[le]; gd = N0n + N1n + g2[E2n + le]; val = true; }
    else return;
    int pos;
    if (val) pos = offsets[gd] + atomicAdd(&cur_v[gd], 1);
    else     pos = offsets[gd] + deg_f[gd] + atomicAdd(&cur_i[gd], 1);
    csr[pos] = src;
}

// ---------------- latent MLP: z -> x0 [N2, B, 128] ----------------

__global__ __launch_bounds__(256) void k_latent(const float* __restrict__ z,
                                                const float* __restrict__ W1,
                                                const float* __restrict__ b1,
                                                const float* __restrict__ W2,
                                                const float* __restrict__ b2,
                                                float* __restrict__ x0) {
    __shared__ float col[64];
    const int t = threadIdx.x;
    const int b = t >> 7, l = t & 127;
    const float zv = z[b * 128 + l];
    float h1[64];
#pragma unroll
    for (int k = 0; k < 64; k++) h1[k] = lrelu(zv * W1[k] + b1[k]);
    for (int nn = 0; nn < 8; nn++) {
        const int n = blockIdx.x * 8 + nn;
        if (n >= N2n) break;                 // uniform across block
        if (t < 64) col[t] = W2[t * N2n + n];
        __syncthreads();
        float s = b2[n];
#pragma unroll
        for (int k = 0; k < 64; k++) s += h1[k] * col[k];
        x0[((size_t)n * Bn + b) * 128 + l] = s;
        __syncthreads();
    }
}

// ---------------- dual GEMM: U = x(Wa-Wb)+b, V = x*Wb ----------------
// 128x64 tile, 8x4 per thread. x: [Mrows,K] fp32; W: [2K,COUT] fp32; compact out.

template <int K, int COUT>
__global__ __launch_bounds__(256) void k_gemm_uv(const float* __restrict__ x,
                                                 const float* __restrict__ W,
                                                 const float* __restrict__ bias,
                                                 float* __restrict__ U, float* __restrict__ V,
                                                 int Mrows) {
    constexpr int TM = 128, TN = 64, TK = 32;
    __shared__ float xs[TK][TM + 4];
    __shared__ float wd[TK][TN];
    __shared__ float wb[TK][TN];
    const int t = threadIdx.x;
    const int row0 = blockIdx.x * TM;
    const int col0 = blockIdx.y * TN;
    const int tc = (t & 15) * 4;        // 16 col groups * 4
    const int tr = (t >> 4) * 8;        // 16 row groups * 8
    const int lrow = t >> 1;            // x-load: 128 rows, 2 thr/row
    const int lseg = (t & 1) * 16;      // x-load: 16 consecutive k
    const int wrow = t >> 3;            // w-load: 32 k rows
    const int wseg = (t & 7) * 8;       // w-load: 8 cols
    float accU[8][4] = {}, accV[8][4] = {};

    for (int k0 = 0; k0 < K; k0 += TK) {
        __syncthreads();
        {   // x tile: 4 float4 per thread, transposed store
            float4 a[4] = {{0,0,0,0},{0,0,0,0},{0,0,0,0},{0,0,0,0}};
            const int gr = row0 + lrow;
            if (gr < Mrows) {
                const float4* p = (const float4*)(x + (size_t)gr * K + k0 + lseg);
                a[0] = p[0]; a[1] = p[1]; a[2] = p[2]; a[3] = p[3];
            }
#pragma unroll
            for (int q = 0; q < 4; q++) {
                xs[lseg + 4 * q + 0][lrow] = a[q].x;
                xs[lseg + 4 * q + 1][lrow] = a[q].y;
                xs[lseg + 4 * q + 2][lrow] = a[q].z;
                xs[lseg + 4 * q + 3][lrow] = a[q].w;
            }
        }
        {   // W tiles: rows [0,K) = Wa (mult x_i), rows [K,2K) = Wb (mult x_j - x_i)
            const float* wa = W + (size_t)(k0 + wrow) * COUT + col0 + wseg;
            const float* wbp = wa + (size_t)K * COUT;
            float fa[8], fb[8];
            *(float4*)&fa[0] = ((const float4*)wa)[0];
            *(float4*)&fa[4] = ((const float4*)wa)[1];
            *(float4*)&fb[0] = ((const float4*)wbp)[0];
            *(float4*)&fb[4] = ((const float4*)wbp)[1];
#pragma unroll
            for (int i = 0; i < 8; i++) {
                wd[wrow][wseg + i] = fa[i] - fb[i];
                wb[wrow][wseg + i] = fb[i];
            }
        }
        __syncthreads();
#pragma unroll
        for (int kk = 0; kk < TK; ++kk) {
            const float4 a0 = *(const float4*)&xs[kk][tr];
            const float4 a1 = *(const float4*)&xs[kk][tr + 4];
            const float4 d = *(const float4*)&wd[kk][tc];
            const float4 e = *(const float4*)&wb[kk][tc];
            const float av[8] = {a0.x, a0.y, a0.z, a0.w, a1.x, a1.y, a1.z, a1.w};
            const float dv[4] = {d.x, d.y, d.z, d.w};
            const float ev[4] = {e.x, e.y, e.z, e.w};
#pragma unroll
            for (int i = 0; i < 8; i++)
#pragma unroll
                for (int j = 0; j < 4; j++) {
                    accU[i][j] += av[i] * dv[j];
                    accV[i][j] += av[i] * ev[j];
                }
        }
    }
    float bf4[4];
#pragma unroll
    for (int j = 0; j < 4; j++) bf4[j] = bias[col0 + tc + j];
#pragma unroll
    for (int i = 0; i < 8; i++) {
        const int r = row0 + tr + i;
        if (r < Mrows) {
            const size_t orow = (size_t)r * COUT + col0 + tc;
            float4 uo = {accU[i][0] + bf4[0], accU[i][1] + bf4[1],
                         accU[i][2] + bf4[2], accU[i][3] + bf4[3]};
            float4 vo = {accV[i][0], accV[i][1], accV[i][2], accV[i][3]};
            *(float4*)(U + orow) = uo;
            *(float4*)(V + orow) = vo;
        }
    }
}

// ---------------- dense edge agg (float4/lane, 8-deep gather pipeline) ----------

DEV_INLINE void acc_relu4(float4& acc, const float4 u, const float4 v) {
    acc.x += fmaxf(u.x + v.x, 0.f);
    acc.y += fmaxf(u.y + v.y, 0.f);
    acc.z += fmaxf(u.z + v.z, 0.f);
    acc.w += fmaxf(u.w + v.w, 0.f);
}

template <int C>
__global__ __launch_bounds__(256) void k_edge_agg(const float* __restrict__ U,
                                                  const float* __restrict__ V,
                                                  const int* __restrict__ offsets,
                                                  const int* __restrict__ csr,
                                                  int nbase, int nnodes,
                                                  float* __restrict__ out) {
    constexpr int TPN = C / 4;
    constexpr int NPB = 256 / TPN;
    const int t = threadIdx.x;
    const int sub = t / TPN;
    const int c4 = (t % TPN) * 4;
    const int i = blockIdx.x * NPB + sub;
    if (i >= nnodes) return;
    const int gi = nbase + i;
    const int beg = offsets[gi], end = offsets[gi + 1];
    const float4 u = ntload4(&U[(size_t)i * C + c4]);   // read-once stream: bypass L2
    float4 acc = {0, 0, 0, 0};
    int e = beg;
    for (; e + 8 <= end; e += 8) {
        int j[8];
#pragma unroll
        for (int q = 0; q < 8; q++) j[q] = csr[e + q];
        float4 v[8];
#pragma unroll
        for (int q = 0; q < 8; q++) v[q] = *(const float4*)&V[(size_t)j[q] * C + c4];
#pragma unroll
        for (int q = 0; q < 8; q++) acc_relu4(acc, u, v[q]);
    }
    if (e + 4 <= end) {
        const int j0 = csr[e], j1 = csr[e + 1], j2 = csr[e + 2], j3 = csr[e + 3];
        const float4 v0 = *(const float4*)&V[(size_t)j0 * C + c4];
        const float4 v1 = *(const float4*)&V[(size_t)j1 * C + c4];
        const float4 v2 = *(const float4*)&V[(size_t)j2 * C + c4];
        const float4 v3 = *(const float4*)&V[(size_t)j3 * C + c4];
        acc_relu4(acc, u, v0); acc_relu4(acc, u, v1);
        acc_relu4(acc, u, v2); acc_relu4(acc, u, v3);
        e += 4;
    }
    for (; e < end; ++e) {
        const float4 v = *(const float4*)&V[(size_t)csr[e] * C + c4];
        acc_relu4(acc, u, v);
    }
    const int dg = end - beg;
    const float inv = 1.f / (float)(dg > 0 ? dg : 1);
    float4 o = {acc.x * inv, acc.y * inv, acc.z * inv, acc.w * inv};
    *(float4*)&out[(size_t)i * C + c4] = o;
}

// ---------------- fused dual agg over valid-prefix csr ----------------
// out[i] = lrelu( [ (deg-deg_f)*(relu(u2)+relu(usk)) + sum_{valid j} relu(u2+v2_j)+relu(usk+vsk_j) ] / deg )
// compact U/V on [0,nnz); i>=nnz -> u = bias row. Valid srcs are the prefix
// [offsets[gi], offsets[gi]+deg_f[gi]) of the node's edge list.

template <int C>
__global__ __launch_bounds__(256) void k_edge_agg_fused(const float* __restrict__ U2,
                                                        const float* __restrict__ V2,
                                                        const float* __restrict__ Usk,
                                                        const float* __restrict__ Vsk,
                                                        const float* __restrict__ b2,
                                                        const float* __restrict__ bsk,
                                                        const int* __restrict__ offsets,
                                                        const int* __restrict__ deg_f,
                                                        const int* __restrict__ csr,
                                                        int nbase, int nnodes, int nnz,
                                                        float* __restrict__ out) {
    constexpr int COUTc = C / Bn;
    constexpr int TPN = C / 4;
    constexpr int NPB = 256 / TPN;
    const int t = threadIdx.x;
    const int sub = t / TPN;
    const int c4 = (t % TPN) * 4;
    const int i = blockIdx.x * NPB + sub;
    if (i >= nnodes) return;
    const int gi = nbase + i;
    const int beg = offsets[gi];
    const int dg = offsets[gi + 1] - beg;
    const int df = deg_f[gi];
    const int fe = beg + df;
    const int cb = c4 & (COUTc - 1);
    const float4 u2  = (i < nnz) ? ntload4(&U2[(size_t)i * C + c4])
                                 : *(const float4*)&b2[cb];
    const float4 usk = (i < nnz) ? ntload4(&Usk[(size_t)i * C + c4])
                                 : *(const float4*)&bsk[cb];
    const float cn = (float)(dg - df);   // edges with zero-src: constant message
    float4 acc;
    acc.x = cn * (fmaxf(u2.x, 0.f) + fmaxf(usk.x, 0.f));
    acc.y = cn * (fmaxf(u2.y, 0.f) + fmaxf(usk.y, 0.f));
    acc.z = cn * (fmaxf(u2.z, 0.f) + fmaxf(usk.z, 0.f));
    acc.w = cn * (fmaxf(u2.w, 0.f) + fmaxf(usk.w, 0.f));
    int e = beg;
    for (; e + 4 <= fe; e += 4) {
        const int j0 = csr[e], j1 = csr[e + 1], j2 = csr[e + 2], j3 = csr[e + 3];
        const float4 p0 = *(const float4*)&V2[(size_t)j0 * C + c4];
        const float4 p1 = *(const float4*)&V2[(size_t)j1 * C + c4];
        const float4 p2 = *(const float4*)&V2[(size_t)j2 * C + c4];
        const float4 p3 = *(const float4*)&V2[(size_t)j3 * C + c4];
        const float4 q0 = *(const float4*)&Vsk[(size_t)j0 * C + c4];
        const float4 q1 = *(const float4*)&Vsk[(size_t)j1 * C + c4];
        const float4 q2 = *(const float4*)&Vsk[(size_t)j2 * C + c4];
        const float4 q3 = *(const float4*)&Vsk[(size_t)j3 * C + c4];
        acc_relu4(acc, u2, p0); acc_relu4(acc, u2, p1); acc_relu4(acc, u2, p2); acc_relu4(acc, u2, p3);
        acc_relu4(acc, usk, q0); acc_relu4(acc, usk, q1); acc_relu4(acc, usk, q2); acc_relu4(acc, usk, q3);
    }
    for (; e < fe; ++e) {
        const int j = csr[e];
        const float4 pv = *(const float4*)&V2[(size_t)j * C + c4];
        const float4 qv = *(const float4*)&Vsk[(size_t)j * C + c4];
        acc_relu4(acc, u2, pv); acc_relu4(acc, usk, qv);
    }
    const float inv = 1.f / (float)(dg > 0 ? dg : 1);
    float4 o = {lrelu(acc.x * inv), lrelu(acc.y * inv),
                lrelu(acc.z * inv), lrelu(acc.w * inv)};
    *(float4*)&out[(size_t)i * C + c4] = o;
}

// ---------------- fused final agg + decoder MLP + LayerNorm(3) ----------------

__global__ __launch_bounds__(256) void k_agg_dec(const float* __restrict__ U,
                                                 const float* __restrict__ V,
                                                 const int* __restrict__ offsets,
                                                 const int* __restrict__ csr,
                                                 const float* __restrict__ Wd1,
                                                 const float* __restrict__ bd1,
                                                 const float* __restrict__ Wd2,
                                                 const float* __restrict__ bd2,
                                                 const float* __restrict__ gamma,
                                                 const float* __restrict__ beta,
                                                 float* __restrict__ out) {
    constexpr int C = 128;
    __shared__ float w1[2048];          // Wd1 [64,32]
    __shared__ float w2[96];            // Wd2 [32,3]
    __shared__ float sb1[32], sb2[3], sg[3], sbt[3];
    __shared__ float xs[16 * 66];       // 16 (n,b) rows of 64, stride 66
    __shared__ float hs[16][33];        // h1 per row
    const int t = threadIdx.x;
    for (int i = t; i < 2048; i += 256) w1[i] = Wd1[i];
    if (t < 96) w2[t] = Wd2[t];
    if (t < 32) sb1[t] = bd1[t];
    if (t < 3) { sb2[t] = bd2[t]; sg[t] = gamma[t]; sbt[t] = beta[t]; }

    // --- agg phase: 8 nodes/block, 32 thr/node, float4/lane, 8-deep pipeline ---
    const int sub = t >> 5;
    const int c4 = (t & 31) * 4;        // channel = b*64 + k
    const int i0 = blockIdx.x * 8 + sub;
    float4 r = {0, 0, 0, 0};
    if (i0 < N0n) {
        const int beg = offsets[i0], end = offsets[i0 + 1];
        const float4 u = ntload4(&U[(size_t)i0 * C + c4]);   // read-once: bypass L2
        float4 acc = {0, 0, 0, 0};
        int e = beg;
        for (; e + 8 <= end; e += 8) {
            int j[8];
#pragma unroll
            for (int q = 0; q < 8; q++) j[q] = csr[e + q];
            float4 v[8];
#pragma unroll
            for (int q = 0; q < 8; q++) v[q] = *(const float4*)&V[(size_t)j[q] * C + c4];
#pragma unroll
            for (int q = 0; q < 8; q++) acc_relu4(acc, u, v[q]);
        }
        if (e + 4 <= end) {
            const int j0 = csr[e], j1 = csr[e + 1], j2 = csr[e + 2], j3 = csr[e + 3];
            const float4 v0 = *(const float4*)&V[(size_t)j0 * C + c4];
            const float4 v1 = *(const float4*)&V[(size_t)j1 * C + c4];
            const float4 v2 = *(const float4*)&V[(size_t)j2 * C + c4];
            const float4 v3 = *(const float4*)&V[(size_t)j3 * C + c4];
            acc_relu4(acc, u, v0); acc_relu4(acc, u, v1);
            acc_relu4(acc, u, v2); acc_relu4(acc, u, v3);
            e += 4;
        }
        for (; e < end; ++e) {
            const float4 v = *(const float4*)&V[(size_t)csr[e] * C + c4];
            acc_relu4(acc, u, v);
        }
        const int dg = end - beg;
        const float inv = 1.f / (float)(dg > 0 ? dg : 1);
        r = {acc.x * inv, acc.y * inv, acc.z * inv, acc.w * inv};
    }
    // stage into LDS: row = sub*2 + b, col = k
    {
        const int rrow = sub * 2 + (c4 >> 6);
        const int rk = c4 & 63;
        float* xp = &xs[rrow * 66 + rk];
        xp[0] = r.x; xp[1] = r.y; xp[2] = r.z; xp[3] = r.w;
    }
    __syncthreads();

    // --- decoder phase: 16 rows x 16 threads ---
    const int drow = t >> 4;
    const int l16 = t & 15;
    float h1a = sb1[l16], h1b = sb1[l16 + 16];
    const float* xrow = &xs[drow * 66];
#pragma unroll 8
    for (int k = 0; k < 64; k++) {
        const float xk = xrow[k];
        h1a += xk * w1[k * 32 + l16];
        h1b += xk * w1[k * 32 + l16 + 16];
    }
    hs[drow][l16] = lrelu(h1a);
    hs[drow][l16 + 16] = lrelu(h1b);
    __syncthreads();

    // --- h2 + LN: one thread per row ---
    if (t < 16) {
        const int node = t >> 1, b = t & 1;
        const int n = blockIdx.x * 8 + node;
        if (n < N0n) {
            float h2[3];
#pragma unroll
            for (int j = 0; j < 3; j++) {
                float s = sb2[j];
#pragma unroll
                for (int c = 0; c < 32; c++) s += hs[t][c] * w2[c * 3 + j];
                h2[j] = s;
            }
            const float mu = (h2[0] + h2[1] + h2[2]) * (1.f / 3.f);
            const float d0 = h2[0] - mu, d1 = h2[1] - mu, d2 = h2[2] - mu;
            const float var = (d0 * d0 + d1 * d1 + d2 * d2) * (1.f / 3.f);
            const float inv = rsqrtf(var + 1e-5f);
            const size_t ob = (size_t)b * N0n * 3 + (size_t)n * 3;
            out[ob + 0] = d0 * inv * sg[0] + sbt[0];
            out[ob + 1] = d1 * inv * sg[1] + sbt[1];
            out[ob + 2] = d2 * inv * sg[2] + sbt[2];
        }
    }
}

// ---------------- launch ----------------

extern "C" void kernel_launch(void* const* d_in, const int* in_sizes, int n_in,
                              void* d_out, int out_size, void* d_ws, size_t ws_size,
                              hipStream_t stream) {
    (void)in_sizes; (void)n_in; (void)out_size; (void)ws_size;
    const float* z   = (const float*)d_in[0];
    const int* g0    = (const int*)d_in[1];
    const int* g1    = (const int*)d_in[2];
    const int* g2    = (const int*)d_in[3];
    const float* W_up1 = (const float*)d_in[6];
    const float* b_up1 = (const float*)d_in[7];
    const float* W_up2 = (const float*)d_in[8];
    const float* b_up2 = (const float*)d_in[9];
    const float* Wb    = (const float*)d_in[10];
    const float* bb    = (const float*)d_in[11];
    const float* l0_W1 = (const float*)d_in[12];
    const float* l0_b1 = (const float*)d_in[13];
    const float* l0_W2 = (const float*)d_in[14];
    const float* l0_b2 = (const float*)d_in[15];
    const float* l0_Wsk = (const float*)d_in[16];
    const float* l0_bsk = (const float*)d_in[17];
    const float* l1_W1 = (const float*)d_in[18];
    const float* l1_b1 = (const float*)d_in[19];
    const float* l1_W2 = (const float*)d_in[20];
    const float* l1_b2 = (const float*)d_in[21];
    const float* l1_Wsk = (const float*)d_in[22];
    const float* l1_bsk = (const float*)d_in[23];
    const float* Wf    = (const float*)d_in[24];
    const float* bf_   = (const float*)d_in[25];
    const float* Wd1   = (const float*)d_in[26];
    const float* bd1   = (const float*)d_in[27];
    const float* Wd2   = (const float*)d_in[28];
    const float* bd2   = (const float*)d_in[29];
    const float* gamma = (const float*)d_in[30];
    const float* beta  = (const float*)d_in[31];

    char* p = (char*)d_ws;
    auto alloc = [&](size_t bytes) -> char* {
        char* r = p; p += (bytes + 255) & ~(size_t)255; return r;
    };
    int* offsets   = (int*)alloc((size_t)(NT + 1) * 4);
    int* partials  = (int*)alloc(128 * 4);
    int* degcur    = (int*)alloc((size_t)4 * NT * 4);
    int* deg = degcur; int* deg_f = degcur + NT;
    int* cur_v = degcur + 2 * NT; int* cur_i = degcur + 3 * NT;
    int* csr   = (int*)alloc((size_t)ET * 4);

    // pooled slabs (fp32): A,B,C = 12.8M floats (51.2 MB) each, D = 3.2M floats.
    constexpr size_t SLOT = (size_t)N0n * Bn * 64;   // 12.8M floats
    constexpr size_t M1 = 1600000;                    // 1.6M-float granule
    float* A = (float*)alloc(SLOT * 4);
    float* B = (float*)alloc(SLOT * 4);
    float* C = (float*)alloc(SLOT * 4);
    float* D = (float*)alloc((size_t)N1n * Bn * 64 * 4);

    // --- CSR build (single csr, valid-prefix partitioned) ---
    hipMemsetAsync(degcur, 0, (size_t)4 * NT * 4, stream);
    k_deg_count<<<(ET + 255) / 256, 256, 0, stream>>>(g0, g1, g2, deg, deg_f);
    k_scan1<<<NCHUNK, 256, 0, stream>>>(deg, offsets, partials);
    k_scan23<<<(NT + 255) / 256, 256, 0, stream>>>(partials, offsets);
    k_csr_fill<<<(ET + 255) / 256, 256, 0, stream>>>(g0, g1, g2, offsets, deg_f,
                                                     cur_v, cur_i, csr);

    const int nb2 = N0n + N1n;   // g2 node base in offsets
    const int nb1 = N0n;         // g1 node base

    // --- latent -> x0 [N2,B,128] @ A[0,M1) ---
    float* x0 = A;
    k_latent<<<(N2n + 7) / 8, 256, 0, stream>>>(z, W_up1, b_up1, W_up2, b_up2, x0);

    // --- conv1 (g2, 128->256): U@A[M1,3M1) V@A[3M1,5M1) -> xc1 @ A[5M1,7M1) ---
    float* xc1 = A + 5 * M1;
    k_gemm_uv<128, 256><<<dim3(98, 4), 256, 0, stream>>>(x0, Wb, bb, A + M1, A + 3 * M1, N2n * Bn);
    k_edge_agg<512><<<(N2n + 1) / 2, 256, 0, stream>>>(A + M1, A + 3 * M1, offsets, csr, nb2, N2n, xc1);

    // --- l0_W1 (g2, 256->64): U@A[7M1,+.5) V@A[7.5M1,8M1) -> t1 @ A[0,M1) (x0 dead) ---
    float* t1 = A;
    k_gemm_uv<256, 64><<<dim3(98, 1), 256, 0, stream>>>(xc1, l0_W1, l0_b1,
                                                        A + 7 * M1, A + 7 * M1 + 800000, N2n * Bn);
    k_edge_agg<128><<<(N2n + 7) / 8, 256, 0, stream>>>(A + 7 * M1, A + 7 * M1 + 800000,
                                                       offsets, csr, nb2, N2n, t1);

    // --- l0_W2 GEMM (64->128): t1 -> U2@B[0,M1) V2@B[M1,2M1) ---
    k_gemm_uv<64, 128><<<dim3(98, 2), 256, 0, stream>>>(t1, l0_W2, l0_b2, B, B + M1, N2n * Bn);
    // --- skip0 GEMM (256->128): xc1 -> Usk@B[2M1,3M1) Vsk@B[3M1,4M1) ---
    k_gemm_uv<256, 128><<<dim3(98, 2), 256, 0, stream>>>(xc1, l0_Wsk, l0_bsk,
                                                         B + 2 * M1, B + 3 * M1, N2n * Bn);
    // --- fused layer0 agg (g1, C=256, nnz=N2n, valid-prefix): -> x1 @ B[4M1,8M1) ---
    float* x1 = B + 4 * M1;
    k_edge_agg_fused<256><<<(N1n + 3) / 4, 256, 0, stream>>>(B, B + M1, B + 2 * M1, B + 3 * M1,
                                                             l0_b2, l0_bsk, offsets, deg_f, csr,
                                                             nb1, N1n, N2n, x1);

    // --- l1_W1 (g1, 128->64): U@A[0,2M1) V@A[2M1,4M1) -> t2 @ D ---
    float* t2 = D;
    k_gemm_uv<128, 64><<<dim3(391, 1), 256, 0, stream>>>(x1, l1_W1, l1_b1, A, A + 2 * M1, N1n * Bn);
    k_edge_agg<128><<<(N1n + 7) / 8, 256, 0, stream>>>(A, A + 2 * M1, offsets, csr, nb1, N1n, t2);

    // --- l1_W2 GEMM (64->64): t2 -> U2@A[0,2M1) V2@A[2M1,4M1) ---
    k_gemm_uv<64, 64><<<dim3(391, 1), 256, 0, stream>>>(t2, l1_W2, l1_b2, A, A + 2 * M1, N1n * Bn);
    // --- skip1 GEMM (128->64): x1 -> Usk@A[4M1,6M1) Vsk@A[6M1,8M1) ---
    k_gemm_uv<128, 64><<<dim3(391, 1), 256, 0, stream>>>(x1, l1_Wsk, l1_bsk,
                                                         A + 4 * M1, A + 6 * M1, N1n * Bn);
    // --- fused layer1 agg (g0, C=128, nnz=N1n, valid-prefix): -> x2 @ C ---
    float* x2 = C;
    k_edge_agg_fused<128><<<(N0n + 7) / 8, 256, 0, stream>>>(A, A + 2 * M1, A + 4 * M1, A + 6 * M1,
                                                             l1_b2, l1_bsk, offsets, deg_f, csr,
                                                             0, N0n, N1n, x2);

    // --- final conv (g0, 64->64): x2 -> Uf@A (full) Vf@B (full) ---
    k_gemm_uv<64, 64><<<dim3(1563, 1), 256, 0, stream>>>(x2, Wf, bf_, A, B, N0n * Bn);
    // --- fused final agg + decoder + LN -> d_out ---
    k_agg_dec<<<(N0n + 7) / 8, 256, 0, stream>>>(A, B, offsets, csr,
                                                 Wd1, bd1, Wd2, bd2, gamma, beta,
                                                 (float*)d_out);
}